// Round 13
// baseline (98.859 us; speedup 1.0000x reference)
//
#include <hip/hip_runtime.h>

#define N_NODES 50000
#define N_EDGES 600000
#define D 128
#define SB 98              // super-buckets of 512 rows (ceil(50000/512))
#define NSEG (2 * SB)      // per-support segments
#define CAP 8192           // fixed per-segment capacity (mean 6144 + 26 sigma)
#define HISTBLK 2048
#define BINBLK 4096
#define HIST_BLOCKS ((N_EDGES + HISTBLK - 1) / HISTBLK)  // 293
#define BIN_BLOCKS ((N_EDGES + BINBLK - 1) / BINBLK)     // 147
#define GEMM_BLOCKS ((N_NODES + 63) / 64)                // 782 (256-thr tiles)
#define GEMM_A 498                                       // tiles in bin launch
#define GEMM_B 71            // 1024-thr blocks in sort launch (71*256=18176)
#define GEMM_B_ROWBASE (GEMM_A * 64)                     // 31872
#define SPMM_BLOCKS 2048
#define SPMM_WAVES (SPMM_BLOCKS * 4)

typedef __attribute__((ext_vector_type(8))) short short8v;  // 8 bf16
typedef __attribute__((ext_vector_type(4))) float f32x4;

__device__ __forceinline__ unsigned short f2bf(float f) {
  unsigned u = __float_as_uint(f);
  return (unsigned short)((u + 0x7FFFu + ((u >> 16) & 1u)) >> 16);
}

// ============================================================================
// W-fragment pack: Wpack[sup][ct(8)][ks(4)][lane(64)][i(8)] = bf16(W[k][d])
//   k = ks*32 + (lane>>4)*8 + i,  d = ct*16 + (lane&15)
// ============================================================================
__device__ __forceinline__ void wpack_one(int idx, const float* __restrict__ W0,
                                          const float* __restrict__ W1,
                                          unsigned short* __restrict__ wpack) {
  const int sup = idx >> 11;
  const int ct = (idx >> 8) & 7;
  const int ks = (idx >> 6) & 3;
  const int l = idx & 63;
  const int q = l >> 4;
  const int c = l & 15;
  const float* W = (sup == 0) ? W0 : W1;
  const int d = ct * 16 + c;
  unsigned short v[8];
#pragma unroll
  for (int i = 0; i < 8; ++i) {
    const int k = ks * 32 + q * 8 + i;
    v[i] = f2bf(W[k * D + d]);
  }
  *(uint4*)(wpack + (size_t)idx * 8) = *(uint4*)v;
}

// ============================================================================
// MFMA GEMM body, templated on waves/block. Block covers NW*16 rows.
// ============================================================================
template <int NW>
__device__ __forceinline__ void gemm_body(
    int block_rowbase, const float* __restrict__ x,
    const unsigned short* __restrict__ wpack, unsigned short* __restrict__ preb,
    unsigned short (*sbuf)[136]) {
  const int t = threadIdx.x;
  const int w = t >> 6;
  const int lane = t & 63;
  const int q = lane >> 4;
  const int c = lane & 15;
  const int arow = block_rowbase + w * 16 + c;

  short8v afrag[4];
#pragma unroll
  for (int ks = 0; ks < 4; ++ks) {
    const int k0 = ks * 32 + q * 8;
    float4 u0 = make_float4(0.f, 0.f, 0.f, 0.f);
    float4 u1 = u0;
    if (arow < N_NODES) {
      u0 = *(const float4*)(x + (size_t)arow * D + k0);
      u1 = *(const float4*)(x + (size_t)arow * D + k0 + 4);
    }
    unsigned short a[8];
    a[0] = f2bf(u0.x); a[1] = f2bf(u0.y); a[2] = f2bf(u0.z); a[3] = f2bf(u0.w);
    a[4] = f2bf(u1.x); a[5] = f2bf(u1.y); a[6] = f2bf(u1.z); a[7] = f2bf(u1.w);
    afrag[ks] = *(const short8v*)a;
  }

  const short8v* wp = (const short8v*)wpack;
#pragma unroll
  for (int sup = 0; sup < 2; ++sup) {
    unsigned short* pb = preb + (size_t)sup * N_NODES * D;
#pragma unroll
    for (int ct = 0; ct < 8; ++ct) {
      f32x4 acc = {0.f, 0.f, 0.f, 0.f};
#pragma unroll
      for (int ks = 0; ks < 4; ++ks) {
        const short8v bfrag = wp[((sup * 8 + ct) * 4 + ks) * 64 + lane];
        acc = __builtin_amdgcn_mfma_f32_16x16x32_bf16(afrag[ks], bfrag, acc,
                                                      0, 0, 0);
      }
#pragma unroll
      for (int j = 0; j < 4; ++j)
        sbuf[w * 16 + q * 4 + j][ct * 16 + c] = f2bf(acc[j]);
    }
    __syncthreads();
#pragma unroll
    for (int it = 0; it < 4; ++it) {
      const int idx = t + it * (NW * 64);
      const int row = idx >> 4;
      const int dseg = (idx & 15) * 8;
      const uint4 v = *(const uint4*)&sbuf[row][dseg];
      const int grow = block_rowbase + row;
      if (grow < N_NODES) *(uint4*)(pb + (size_t)grow * D + dseg) = v;
    }
    __syncthreads();
  }
}

// ============================================================================
// Counting-sort body (1024 threads): segment [s, s+n) of cv, rows sb*512..
// ============================================================================
__device__ __forceinline__ void sort_body(int sup, int sb, int s, int n,
                                          int2* __restrict__ cv,
                                          int* __restrict__ rs_s,
                                          int* __restrict__ rs_e,
                                          int* cnt, int* base, int* off) {
  const int t = threadIdx.x;
  if (t < 512) {
    cnt[t] = 0;
    off[t] = 0;
  }
  __syncthreads();

  int2 ed[8];
#pragma unroll
  for (int k = 0; k < 8; ++k) {
    const int i = t + k * 1024;
    if (i < n) {
      ed[k] = cv[s + i];
      atomicAdd(&cnt[(ed[k].x >> 16) & 511], 1);
    }
  }
  __syncthreads();

  if (t < 64) {
    int v[8];
    int ssum = 0;
#pragma unroll
    for (int k = 0; k < 8; ++k) {
      v[k] = cnt[t * 8 + k];
      ssum += v[k];
    }
    int run = ssum;
#pragma unroll
    for (int off2 = 1; off2 < 64; off2 <<= 1) {
      const int u = __shfl_up(run, off2);
      if (t >= off2) run += u;
    }
    int excl = run - ssum;
#pragma unroll
    for (int k = 0; k < 8; ++k) {
      base[t * 8 + k] = excl;
      excl += v[k];
    }
  }
  __syncthreads();

  if (t < 512) {
    const int row = sb * 512 + t;
    if (row < N_NODES) {
      rs_s[sup * N_NODES + row] = s + base[t];
      rs_e[sup * N_NODES + row] = s + base[t] + cnt[t];
    }
  }

#pragma unroll
  for (int k = 0; k < 8; ++k) {
    const int i = t + k * 1024;
    if (i < n) {
      const int rl = (ed[k].x >> 16) & 511;
      const int pos = base[rl] + atomicAdd(&off[rl], 1);
      cv[s + pos] = ed[k];
    }
  }
}

// ============================================================================
// Bin body (CAPPED or exact): block-sorts 4096 edges by super-bucket in LDS,
// bump-allocates contiguous runs.  cv.x = col|rloc<<16|sb<<25, cv.y = val.
// ============================================================================
struct BinSmem {
  int hist[SB];
  int lstart[SB];
  int lpos[SB];
  int gbase[SB];
  int2 stage[BINBLK];  // 32 KB
};

template <bool CAPPED>
__device__ __forceinline__ void bin_body(
    int bx, const int* __restrict__ rows0, const int* __restrict__ cols0,
    const float* __restrict__ vals0, const int* __restrict__ rows1,
    const int* __restrict__ cols1, const float* __restrict__ vals1,
    int* __restrict__ fillc, int2* __restrict__ cv, BinSmem* sm) {
  const int t = threadIdx.x;
  const int sup = (bx >= BIN_BLOCKS) ? 1 : 0;
  const int bb = bx - sup * BIN_BLOCKS;
  const int* rows = sup ? rows1 : rows0;
  const int* cols = sup ? cols1 : cols0;
  const float* vals = sup ? vals1 : vals0;
  const int ebase = bb * BINBLK;
  const int nloc = min(BINBLK, N_EDGES - ebase);

  if (t < SB) sm->hist[t] = 0;
  __syncthreads();

  int myr[16], myc[16];
  float myv[16];
#pragma unroll
  for (int k = 0; k < 16; ++k) {
    const int i = t + k * 256;
    myr[k] = -1;
    if (i < nloc) {
      myr[k] = rows[ebase + i];
      myc[k] = cols[ebase + i];
      myv[k] = vals[ebase + i];
      atomicAdd(&sm->hist[myr[k] >> 9], 1);
    }
  }
  __syncthreads();

  if (t < 64) {
    const int g0 = 2 * t, g1 = 2 * t + 1;
    const int v0 = (g0 < SB) ? sm->hist[g0] : 0;
    const int v1 = (g1 < SB) ? sm->hist[g1] : 0;
    const int ssum = v0 + v1;
    int run = ssum;
#pragma unroll
    for (int off = 1; off < 64; off <<= 1) {
      const int u = __shfl_up(run, off);
      if (t >= off) run += u;
    }
    const int excl = run - ssum;
    if (g0 < SB) {
      sm->lstart[g0] = excl;
      sm->lpos[g0] = excl;
    }
    if (g1 < SB) {
      sm->lstart[g1] = excl + v0;
      sm->lpos[g1] = excl + v0;
    }
  }
  __syncthreads();

#pragma unroll
  for (int k = 0; k < 16; ++k) {
    if (myr[k] >= 0) {
      const int sb = myr[k] >> 9;
      const int p = atomicAdd(&sm->lpos[sb], 1);
      sm->stage[p] = make_int2(myc[k] | ((myr[k] & 511) << 16) | (sb << 25),
                               __float_as_int(myv[k]));
    }
  }
  if (t < SB && sm->hist[t] > 0) {
    const int seg = sup * SB + t;
    const int bump = atomicAdd(&fillc[seg], sm->hist[t]);
    sm->gbase[t] = (CAPPED ? seg * CAP : 0) + bump;
  }
  __syncthreads();

  for (int i = t; i < nloc; i += 256) {
    const int2 ev = sm->stage[i];
    const int sb = ((unsigned)ev.x) >> 25;
    cv[sm->gbase[sb] + (i - sm->lstart[sb])] = ev;
  }
}

// ============================================================================
// Tier A init: blocks 0..15 pack W, block 16 zeroes fillc.
// ============================================================================
__global__ __launch_bounds__(256) void init_kernel(
    const float* __restrict__ W0, const float* __restrict__ W1,
    unsigned short* __restrict__ wpack, int* __restrict__ fillc) {
  const int t = threadIdx.x;
  if (blockIdx.x == 16) {
    if (t < NSEG) fillc[t] = 0;
    return;
  }
  wpack_one(blockIdx.x * 256 + t, W0, W1, wpack);
}

// ============================================================================
// Tier A launch 2: bin (CAPPED, blocks 0..293) + gemm tiles 0..497.
// ============================================================================
union BinGemmSmem {
  BinSmem bin;                   // 34.3 KB
  unsigned short sbuf[64][136];  // 17.4 KB
};

__global__ __launch_bounds__(256) void bingemmA_kernel(
    const int* __restrict__ rows0, const int* __restrict__ cols0,
    const float* __restrict__ vals0, const int* __restrict__ rows1,
    const int* __restrict__ cols1, const float* __restrict__ vals1,
    int* __restrict__ fillc, int2* __restrict__ cv,
    const float* __restrict__ x, const unsigned short* __restrict__ wpack,
    unsigned short* __restrict__ preb) {
  __shared__ BinGemmSmem sm;
  const int bx = blockIdx.x;
  if (bx >= 2 * BIN_BLOCKS) {
    gemm_body<4>((bx - 2 * BIN_BLOCKS) * 64, x, wpack, preb, sm.sbuf);
    return;
  }
  bin_body<true>(bx, rows0, cols0, vals0, rows1, cols1, vals1, fillc, cv,
                 &sm.bin);
}

// ============================================================================
// Tier A launch 3: sort (blocks 0..195, CAPPED segments) + gemm rows
// 31872.. (blocks 196..266, 256 rows each).
// ============================================================================
union SortGemmSmem {
  struct {
    int cnt[512];
    int base[512];
    int off[512];
  } s;                            // 6 KB
  unsigned short sbuf[256][136];  // 69.6 KB
};

__global__ __launch_bounds__(1024) void sortgemm_kernel(
    int* __restrict__ fillc, int2* __restrict__ cv, int* __restrict__ rs_s,
    int* __restrict__ rs_e, const float* __restrict__ x,
    const unsigned short* __restrict__ wpack,
    unsigned short* __restrict__ preb) {
  __shared__ SortGemmSmem sm;
  const int bx = blockIdx.x;
  if (bx < NSEG) {
    const int sup = bx / SB;
    const int sb = bx - sup * SB;
    sort_body(sup, sb, bx * CAP, fillc[bx], cv, rs_s, rs_e, sm.s.cnt,
              sm.s.base, sm.s.off);
  } else {
    gemm_body<16>(GEMM_B_ROWBASE + (bx - NSEG) * 256, x, wpack, preb, sm.sbuf);
  }
}

// ============================================================================
// Tier B: histogram + W prepack
// ============================================================================
__global__ __launch_bounds__(256) void histpack_kernel(
    const int* __restrict__ rows0, const int* __restrict__ rows1,
    int* __restrict__ cnt, const float* __restrict__ W0,
    const float* __restrict__ W1, unsigned short* __restrict__ wpack) {
  const int t = threadIdx.x;
  if (blockIdx.x >= HIST_BLOCKS) {
    wpack_one(((blockIdx.x - HIST_BLOCKS) + 8 * blockIdx.y) * 256 + t, W0, W1,
              wpack);
    return;
  }
  __shared__ int h[SB];
  if (t < SB) h[t] = 0;
  __syncthreads();
  const int sup = blockIdx.y;
  const int* rows = sup ? rows1 : rows0;
  int e = blockIdx.x * HISTBLK + t;
#pragma unroll
  for (int k = 0; k < HISTBLK / 256; ++k, e += 256)
    if (e < N_EDGES) atomicAdd(&h[rows[e] >> 9], 1);
  __syncthreads();
  if (t < SB && h[t] > 0) atomicAdd(&cnt[sup * SB + t], h[t]);
}

// ============================================================================
// Tier B: exclusive scan of the 196 segment counts — single wave
// ============================================================================
__global__ __launch_bounds__(64) void scan196_kernel(
    const int* __restrict__ cnt, int* __restrict__ fillc,
    int* __restrict__ sbstart) {
  const int t = threadIdx.x;
  int v[4];
  int ssum = 0;
#pragma unroll
  for (int k = 0; k < 4; ++k) {
    const int g = t * 4 + k;
    v[k] = (g < NSEG) ? cnt[g] : 0;
    ssum += v[k];
  }
  int run = ssum;
#pragma unroll
  for (int off = 1; off < 64; off <<= 1) {
    const int u = __shfl_up(run, off);
    if (t >= off) run += u;
  }
  int excl = run - ssum;
#pragma unroll
  for (int k = 0; k < 4; ++k) {
    const int g = t * 4 + k;
    if (g < NSEG) {
      fillc[g] = excl;
      sbstart[g] = excl;
    }
    excl += v[k];
  }
  if (t == 63) sbstart[NSEG] = 2 * N_EDGES;
}

// ============================================================================
// Tier B: fused bin (exact bases) + all gemm tiles
// ============================================================================
__global__ __launch_bounds__(256) void bingemmB_kernel(
    const int* __restrict__ rows0, const int* __restrict__ cols0,
    const float* __restrict__ vals0, const int* __restrict__ rows1,
    const int* __restrict__ cols1, const float* __restrict__ vals1,
    int* __restrict__ fillc, int2* __restrict__ cv,
    const float* __restrict__ x, const unsigned short* __restrict__ wpack,
    unsigned short* __restrict__ preb) {
  __shared__ BinGemmSmem sm;
  const int bx = blockIdx.x;
  if (bx >= 2 * BIN_BLOCKS) {
    gemm_body<4>((bx - 2 * BIN_BLOCKS) * 64, x, wpack, preb, sm.sbuf);
    return;
  }
  bin_body<false>(bx, rows0, cols0, vals0, rows1, cols1, vals1, fillc, cv,
                  &sm.bin);
}

// ============================================================================
// Tier B: standalone sort (exact bases)
// ============================================================================
__global__ __launch_bounds__(1024) void sortB_kernel(
    const int* __restrict__ sbstart, int2* __restrict__ cv,
    int* __restrict__ rs_s, int* __restrict__ rs_e) {
  __shared__ int cnt[512];
  __shared__ int base[512];
  __shared__ int off[512];
  const int sb = blockIdx.x;
  const int sup = blockIdx.y;
  const int seg = sup * SB + sb;
  const int s = sbstart[seg];
  const int n = sbstart[seg + 1] - s;
  sort_body(sup, sb, s, n, cv, rs_s, rs_e, cnt, base, off);
}

// ============================================================================
// Fused SpMM gather: persistent waves, both supports + bias + relu.
// ============================================================================
__global__ __launch_bounds__(256) void spmm_fused_kernel(
    const int* __restrict__ rs_s, const int* __restrict__ rs_e,
    const int2* __restrict__ cv, const unsigned short* __restrict__ preb,
    const float* __restrict__ bias, float* __restrict__ out) {
  const int lane = threadIdx.x & 63;
  const int g = lane >> 4;
  const int dbase = (lane & 15) << 3;
  const int wid = blockIdx.x * 4 + (threadIdx.x >> 6);

  const float4 b0 = *(const float4*)(bias + dbase);
  const float4 b1 = *(const float4*)(bias + dbase + 4);

  for (int row = wid; row < N_NODES; row += SPMM_WAVES) {
    float acc[8];
#pragma unroll
    for (int i = 0; i < 8; ++i) acc[i] = 0.f;

#pragma unroll
    for (int sup = 0; sup < 2; ++sup) {
      const int s = rs_s[sup * N_NODES + row];
      const int e = rs_e[sup * N_NODES + row];
      const unsigned short* pb = preb + (size_t)sup * N_NODES * D;
      int j = s + g;
      for (; j + 4 < e; j += 8) {
        const int2 e0 = cv[j];
        const int2 e1 = cv[j + 4];
        const uint4 q0 = *(const uint4*)(pb + (size_t)(e0.x & 0xFFFF) * D + dbase);
        const uint4 q1 = *(const uint4*)(pb + (size_t)(e1.x & 0xFFFF) * D + dbase);
        const float v0 = __int_as_float(e0.y);
        const float v1 = __int_as_float(e1.y);
        acc[0] = fmaf(v0, __uint_as_float(q0.x << 16), acc[0]);
        acc[1] = fmaf(v0, __uint_as_float(q0.x & 0xFFFF0000u), acc[1]);
        acc[2] = fmaf(v0, __uint_as_float(q0.y << 16), acc[2]);
        acc[3] = fmaf(v0, __uint_as_float(q0.y & 0xFFFF0000u), acc[3]);
        acc[4] = fmaf(v0, __uint_as_float(q0.z << 16), acc[4]);
        acc[5] = fmaf(v0, __uint_as_float(q0.z & 0xFFFF0000u), acc[5]);
        acc[6] = fmaf(v0, __uint_as_float(q0.w << 16), acc[6]);
        acc[7] = fmaf(v0, __uint_as_float(q0.w & 0xFFFF0000u), acc[7]);
        acc[0] = fmaf(v1, __uint_as_float(q1.x << 16), acc[0]);
        acc[1] = fmaf(v1, __uint_as_float(q1.x & 0xFFFF0000u), acc[1]);
        acc[2] = fmaf(v1, __uint_as_float(q1.y << 16), acc[2]);
        acc[3] = fmaf(v1, __uint_as_float(q1.y & 0xFFFF0000u), acc[3]);
        acc[4] = fmaf(v1, __uint_as_float(q1.z << 16), acc[4]);
        acc[5] = fmaf(v1, __uint_as_float(q1.z & 0xFFFF0000u), acc[5]);
        acc[6] = fmaf(v1, __uint_as_float(q1.w << 16), acc[6]);
        acc[7] = fmaf(v1, __uint_as_float(q1.w & 0xFFFF0000u), acc[7]);
      }
      if (j < e) {
        const int2 e0 = cv[j];
        const uint4 q0 = *(const uint4*)(pb + (size_t)(e0.x & 0xFFFF) * D + dbase);
        const float v0 = __int_as_float(e0.y);
        acc[0] = fmaf(v0, __uint_as_float(q0.x << 16), acc[0]);
        acc[1] = fmaf(v0, __uint_as_float(q0.x & 0xFFFF0000u), acc[1]);
        acc[2] = fmaf(v0, __uint_as_float(q0.y << 16), acc[2]);
        acc[3] = fmaf(v0, __uint_as_float(q0.y & 0xFFFF0000u), acc[3]);
        acc[4] = fmaf(v0, __uint_as_float(q0.z << 16), acc[4]);
        acc[5] = fmaf(v0, __uint_as_float(q0.z & 0xFFFF0000u), acc[5]);
        acc[6] = fmaf(v0, __uint_as_float(q0.w << 16), acc[6]);
        acc[7] = fmaf(v0, __uint_as_float(q0.w & 0xFFFF0000u), acc[7]);
      }
    }

#pragma unroll
    for (int i = 0; i < 8; ++i) {
      acc[i] += __shfl_xor(acc[i], 16);
      acc[i] += __shfl_xor(acc[i], 32);
    }

    if (g == 0) {
      float4 r0, r1;
      r0.x = fmaxf(acc[0] + b0.x, 0.f);
      r0.y = fmaxf(acc[1] + b0.y, 0.f);
      r0.z = fmaxf(acc[2] + b0.z, 0.f);
      r0.w = fmaxf(acc[3] + b0.w, 0.f);
      r1.x = fmaxf(acc[4] + b1.x, 0.f);
      r1.y = fmaxf(acc[5] + b1.y, 0.f);
      r1.z = fmaxf(acc[6] + b1.z, 0.f);
      r1.w = fmaxf(acc[7] + b1.w, 0.f);
      float* op = out + (size_t)row * D + dbase;
      *(float4*)op = r0;
      *(float4*)(op + 4) = r1;
    }
  }
}

// ============================================================================
// Fallback: fp32 gemm + atomic scatter (used only if workspace too small)
// ============================================================================
__global__ __launch_bounds__(256) void gemm_f32_kernel(
    const float* __restrict__ x, const float* __restrict__ W,
    float* __restrict__ pre) {
  const int tid = threadIdx.x;
  const int nloc = (tid >> 5) << 3;
  const int d4 = (tid & 31) << 2;
  const int nbase = blockIdx.x * 64;
  __shared__ float xs[64][D];
  {
    float4* xs4 = (float4*)(&xs[0][0]);
    const float4* xg4 = (const float4*)x;
#pragma unroll
    for (int i = 0; i < 8; ++i) {
      const int idx = tid + i * 256;
      const int row = nbase + (idx >> 5);
      xs4[idx] = (row < N_NODES) ? xg4[(size_t)row * 32 + (idx & 31)]
                                 : make_float4(0.f, 0.f, 0.f, 0.f);
    }
  }
  __syncthreads();
  float4 acc[8];
#pragma unroll
  for (int i = 0; i < 8; ++i) acc[i] = make_float4(0.f, 0.f, 0.f, 0.f);
  for (int k = 0; k < D; ++k) {
    const float4 w = *(const float4*)(W + k * D + d4);
#pragma unroll
    for (int i = 0; i < 8; ++i) {
      const float xv = xs[nloc + i][k];
      acc[i].x = fmaf(xv, w.x, acc[i].x);
      acc[i].y = fmaf(xv, w.y, acc[i].y);
      acc[i].z = fmaf(xv, w.z, acc[i].z);
      acc[i].w = fmaf(xv, w.w, acc[i].w);
    }
  }
#pragma unroll
  for (int i = 0; i < 8; ++i) {
    const int n = nbase + nloc + i;
    if (n < N_NODES) *(float4*)(pre + (size_t)n * D + d4) = acc[i];
  }
}

__global__ __launch_bounds__(256) void spmm_scatter_kernel(
    const int* __restrict__ rows, const int* __restrict__ cols,
    const float* __restrict__ vals, const float* __restrict__ pre,
    float* __restrict__ out) {
  const long long idx = (long long)blockIdx.x * blockDim.x + threadIdx.x;
  const int e = (int)(idx >> 6);
  if (e >= N_EDGES) return;
  const int dd = ((int)idx & 63) << 1;
  const int r = rows[e];
  const int c = cols[e];
  const float v = vals[e];
  const float2 p = *(const float2*)(pre + (size_t)c * D + dd);
  float* outp = out + (size_t)r * D + dd;
  atomicAdd(outp + 0, v * p.x);
  atomicAdd(outp + 1, v * p.y);
}

__global__ __launch_bounds__(256) void bias_relu_kernel(
    float* __restrict__ out, const float* __restrict__ b) {
  const int idx = blockIdx.x * blockDim.x + threadIdx.x;
  float4 v = ((float4*)out)[idx];
  const float4 bb = ((const float4*)b)[idx & 31];
  v.x = fmaxf(v.x + bb.x, 0.f);
  v.y = fmaxf(v.y + bb.y, 0.f);
  v.z = fmaxf(v.z + bb.z, 0.f);
  v.w = fmaxf(v.w + bb.w, 0.f);
  ((float4*)out)[idx] = v;
}

extern "C" void kernel_launch(void* const* d_in, const int* in_sizes, int n_in,
                              void* d_out, int out_size, void* d_ws,
                              size_t ws_size, hipStream_t stream) {
  const float* x = (const float*)d_in[0];
  const float* W0 = (const float*)d_in[1];
  const float* W1 = (const float*)d_in[2];
  const float* b = (const float*)d_in[3];
  const int* rows0 = (const int*)d_in[4];
  const int* cols0 = (const int*)d_in[5];
  const float* vals0 = (const float*)d_in[6];
  const int* rows1 = (const int*)d_in[7];
  const int* cols1 = (const int*)d_in[8];
  const float* vals1 = (const float*)d_in[9];
  float* out = (float*)d_out;

  auto align_up = [](size_t v) { return (v + 255) & ~(size_t)255; };
  const size_t PREB = align_up((size_t)2 * N_NODES * D * 2);  // 25.6 MB bf16
  const size_t FILLC = align_up((size_t)NSEG * 4);
  const size_t RS1 = align_up((size_t)2 * N_NODES * 4);  // 400 KB each
  const size_t WPACK = align_up((size_t)2 * D * D * 2);  // 64 KB

  // Tier A: fixed-capacity segments (no hist/scan/memset)
  const size_t CVC = align_up((size_t)NSEG * CAP * 8);  // 12.85 MB
  const size_t NEED_A = PREB + CVC + FILLC + 2 * RS1 + WPACK;  // ~39.4 MB
  // Tier B: exact bases
  const size_t CV = align_up((size_t)2 * N_EDGES * 8);  // 9.6 MB
  const size_t CNT = align_up((size_t)NSEG * 4);
  const size_t SBSTART = align_up((size_t)(NSEG + 1) * 4);
  const size_t NEED_B = PREB + CV + CNT + FILLC + SBSTART + 2 * RS1 + WPACK;

  char* wsc = (char*)d_ws;

  if (ws_size >= NEED_A) {
    unsigned short* preb = (unsigned short*)wsc;
    int2* cv = (int2*)(wsc + PREB);
    int* fillc = (int*)(wsc + PREB + CVC);
    int* rs_s = (int*)(wsc + PREB + CVC + FILLC);
    int* rs_e = (int*)(wsc + PREB + CVC + FILLC + RS1);
    unsigned short* wpack =
        (unsigned short*)(wsc + PREB + CVC + FILLC + 2 * RS1);

    init_kernel<<<17, 256, 0, stream>>>(W0, W1, wpack, fillc);
    bingemmA_kernel<<<2 * BIN_BLOCKS + GEMM_A, 256, 0, stream>>>(
        rows0, cols0, vals0, rows1, cols1, vals1, fillc, cv, x, wpack, preb);
    sortgemm_kernel<<<NSEG + GEMM_B, 1024, 0, stream>>>(fillc, cv, rs_s, rs_e,
                                                        x, wpack, preb);
    spmm_fused_kernel<<<SPMM_BLOCKS, 256, 0, stream>>>(rs_s, rs_e, cv, preb, b,
                                                       out);
  } else if (ws_size >= NEED_B) {
    unsigned short* preb = (unsigned short*)wsc;
    int2* cv = (int2*)(wsc + PREB);
    int* cnt = (int*)(wsc + PREB + CV);
    int* fillc = (int*)(wsc + PREB + CV + CNT);
    int* sbstart = (int*)(wsc + PREB + CV + CNT + FILLC);
    int* rs_s = (int*)(wsc + PREB + CV + CNT + FILLC + SBSTART);
    int* rs_e = (int*)(wsc + PREB + CV + CNT + FILLC + SBSTART + RS1);
    unsigned short* wpack =
        (unsigned short*)(wsc + PREB + CV + CNT + FILLC + SBSTART + 2 * RS1);

    hipMemsetAsync(cnt, 0, (size_t)NSEG * 4, stream);
    histpack_kernel<<<dim3(HIST_BLOCKS + 8, 2), 256, 0, stream>>>(
        rows0, rows1, cnt, W0, W1, wpack);
    scan196_kernel<<<1, 64, 0, stream>>>(cnt, fillc, sbstart);
    bingemmB_kernel<<<2 * BIN_BLOCKS + GEMM_BLOCKS, 256, 0, stream>>>(
        rows0, cols0, vals0, rows1, cols1, vals1, fillc, cv, x, wpack, preb);
    sortB_kernel<<<dim3(SB, 2), 1024, 0, stream>>>(sbstart, cv, rs_s, rs_e);
    spmm_fused_kernel<<<SPMM_BLOCKS, 256, 0, stream>>>(rs_s, rs_e, cv, preb, b,
                                                       out);
  } else {
    float* pre = (float*)wsc;
    hipMemsetAsync(d_out, 0, (size_t)N_NODES * D * 4, stream);
    const int scat_blocks = (N_EDGES * 64 + 255) / 256;
    gemm_f32_kernel<<<GEMM_BLOCKS, 256, 0, stream>>>(x, W0, pre);
    spmm_scatter_kernel<<<scat_blocks, 256, 0, stream>>>(rows0, cols0, vals0,
                                                         pre, out);
    gemm_f32_kernel<<<GEMM_BLOCKS, 256, 0, stream>>>(x, W1, pre);
    spmm_scatter_kernel<<<scat_blocks, 256, 0, stream>>>(rows1, cols1, vals1,
                                                         pre, out);
    bias_relu_kernel<<<(N_NODES * D / 4) / 256, 256, 0, stream>>>(out, b);
  }
}

// Round 14
// 88.435 us; speedup vs baseline: 1.1179x; 1.1179x over previous
//
#include <hip/hip_runtime.h>

#define N_NODES 50000
#define N_EDGES 600000
#define D 128
#define SB 196             // super-buckets of 256 rows (ceil(50000/256))
#define SBROWS 256
#define SBSHIFT 8
#define NSEG (2 * SB)      // 392 per-support segments
#define CAP 4096           // per-segment capacity (mean 3061 + ~19 sigma)
#define HISTBLK 2048
#define BINBLK 4096
#define HIST_BLOCKS ((N_EDGES + HISTBLK - 1) / HISTBLK)  // 293
#define BIN_BLOCKS ((N_EDGES + BINBLK - 1) / BINBLK)     // 147
#define GEMM_BLOCKS ((N_NODES + 63) / 64)                // 782
#define SPMM_BLOCKS 2048
#define SPMM_WAVES (SPMM_BLOCKS * 4)

typedef __attribute__((ext_vector_type(8))) short short8v;  // 8 bf16
typedef __attribute__((ext_vector_type(4))) float f32x4;

__device__ __forceinline__ unsigned short f2bf(float f) {
  unsigned u = __float_as_uint(f);
  return (unsigned short)((u + 0x7FFFu + ((u >> 16) & 1u)) >> 16);
}

// ============================================================================
// W-fragment pack: Wpack[sup][ct(8)][ks(4)][lane(64)][i(8)] = bf16(W[k][d])
//   k = ks*32 + (lane>>4)*8 + i,  d = ct*16 + (lane&15)
// ============================================================================
__device__ __forceinline__ void wpack_one(int idx, const float* __restrict__ W0,
                                          const float* __restrict__ W1,
                                          unsigned short* __restrict__ wpack) {
  const int sup = idx >> 11;
  const int ct = (idx >> 8) & 7;
  const int ks = (idx >> 6) & 3;
  const int l = idx & 63;
  const int q = l >> 4;
  const int c = l & 15;
  const float* W = (sup == 0) ? W0 : W1;
  const int d = ct * 16 + c;
  unsigned short v[8];
#pragma unroll
  for (int i = 0; i < 8; ++i) {
    const int k = ks * 32 + q * 8 + i;
    v[i] = f2bf(W[k * D + d]);
  }
  *(uint4*)(wpack + (size_t)idx * 8) = *(uint4*)v;
}

// ============================================================================
// MFMA GEMM body (4 waves, 64 rows/block).
// ============================================================================
__device__ __forceinline__ void gemm_body64(
    int block_rowbase, const float* __restrict__ x,
    const unsigned short* __restrict__ wpack, unsigned short* __restrict__ preb,
    unsigned short (*sbuf)[136]) {
  const int t = threadIdx.x;
  const int w = t >> 6;
  const int lane = t & 63;
  const int q = lane >> 4;
  const int c = lane & 15;
  const int arow = block_rowbase + w * 16 + c;

  short8v afrag[4];
#pragma unroll
  for (int ks = 0; ks < 4; ++ks) {
    const int k0 = ks * 32 + q * 8;
    float4 u0 = make_float4(0.f, 0.f, 0.f, 0.f);
    float4 u1 = u0;
    if (arow < N_NODES) {
      u0 = *(const float4*)(x + (size_t)arow * D + k0);
      u1 = *(const float4*)(x + (size_t)arow * D + k0 + 4);
    }
    unsigned short a[8];
    a[0] = f2bf(u0.x); a[1] = f2bf(u0.y); a[2] = f2bf(u0.z); a[3] = f2bf(u0.w);
    a[4] = f2bf(u1.x); a[5] = f2bf(u1.y); a[6] = f2bf(u1.z); a[7] = f2bf(u1.w);
    afrag[ks] = *(const short8v*)a;
  }

  const short8v* wp = (const short8v*)wpack;
#pragma unroll
  for (int sup = 0; sup < 2; ++sup) {
    unsigned short* pb = preb + (size_t)sup * N_NODES * D;
#pragma unroll
    for (int ct = 0; ct < 8; ++ct) {
      f32x4 acc = {0.f, 0.f, 0.f, 0.f};
#pragma unroll
      for (int ks = 0; ks < 4; ++ks) {
        const short8v bfrag = wp[((sup * 8 + ct) * 4 + ks) * 64 + lane];
        acc = __builtin_amdgcn_mfma_f32_16x16x32_bf16(afrag[ks], bfrag, acc,
                                                      0, 0, 0);
      }
#pragma unroll
      for (int j = 0; j < 4; ++j)
        sbuf[w * 16 + q * 4 + j][ct * 16 + c] = f2bf(acc[j]);
    }
    __syncthreads();
#pragma unroll
    for (int it = 0; it < 4; ++it) {
      const int idx = t + it * 256;
      const int row = idx >> 4;
      const int dseg = (idx & 15) * 8;
      const uint4 v = *(const uint4*)&sbuf[row][dseg];
      const int grow = block_rowbase + row;
      if (grow < N_NODES) *(uint4*)(pb + (size_t)grow * D + dseg) = v;
    }
    __syncthreads();
  }
}

// ============================================================================
// Counting-sort body (1024 threads): segment [s, s+n) of cv (n <= CAP),
// rows sb*256.. -> row-sorted cv in place + rs_s/rs_e.
// ============================================================================
__device__ __forceinline__ void sort_body(int sup, int sb, int s, int n,
                                          int2* __restrict__ cv,
                                          int* __restrict__ rs_s,
                                          int* __restrict__ rs_e,
                                          int* cnt, int* base, int* off) {
  const int t = threadIdx.x;
  if (t < SBROWS) {
    cnt[t] = 0;
    off[t] = 0;
  }
  __syncthreads();

  int2 ed[4];
#pragma unroll
  for (int k = 0; k < 4; ++k) {
    const int i = t + k * 1024;
    if (i < n) {
      ed[k] = cv[s + i];
      atomicAdd(&cnt[(ed[k].x >> 16) & (SBROWS - 1)], 1);
    }
  }
  __syncthreads();

  // wave-0 exclusive scan of cnt[256]: 4 values/lane + butterfly on sums
  if (t < 64) {
    int v[4];
    int ssum = 0;
#pragma unroll
    for (int k = 0; k < 4; ++k) {
      v[k] = cnt[t * 4 + k];
      ssum += v[k];
    }
    int run = ssum;
#pragma unroll
    for (int off2 = 1; off2 < 64; off2 <<= 1) {
      const int u = __shfl_up(run, off2);
      if (t >= off2) run += u;
    }
    int excl = run - ssum;
#pragma unroll
    for (int k = 0; k < 4; ++k) {
      base[t * 4 + k] = excl;
      excl += v[k];
    }
  }
  __syncthreads();

  if (t < SBROWS) {
    const int row = sb * SBROWS + t;
    if (row < N_NODES) {
      rs_s[sup * N_NODES + row] = s + base[t];
      rs_e[sup * N_NODES + row] = s + base[t] + cnt[t];
    }
  }

#pragma unroll
  for (int k = 0; k < 4; ++k) {
    const int i = t + k * 1024;
    if (i < n) {
      const int rl = (ed[k].x >> 16) & (SBROWS - 1);
      const int pos = base[rl] + atomicAdd(&off[rl], 1);
      cv[s + pos] = ed[k];
    }
  }
}

// ============================================================================
// Bin body: block-sorts 4096 edges by super-bucket in LDS, bump-allocates
// contiguous global runs.  cv.x = col(16) | rloc(8)<<16 | sb(8)<<24.
// ============================================================================
struct BinSmem {
  int hist[SB];
  int lstart[SB];
  int lpos[SB];
  int gbase[SB];
  int2 stage[BINBLK];  // 32 KB (total ~35.1 KB)
};

template <bool CAPPED>
__device__ __forceinline__ void bin_body(
    int bx, const int* __restrict__ rows0, const int* __restrict__ cols0,
    const float* __restrict__ vals0, const int* __restrict__ rows1,
    const int* __restrict__ cols1, const float* __restrict__ vals1,
    int* __restrict__ fillc, int2* __restrict__ cv, BinSmem* sm) {
  const int t = threadIdx.x;
  const int sup = (bx >= BIN_BLOCKS) ? 1 : 0;
  const int bb = bx - sup * BIN_BLOCKS;
  const int* rows = sup ? rows1 : rows0;
  const int* cols = sup ? cols1 : cols0;
  const float* vals = sup ? vals1 : vals0;
  const int ebase = bb * BINBLK;
  const int nloc = min(BINBLK, N_EDGES - ebase);

  if (t < SB) sm->hist[t] = 0;
  __syncthreads();

  int myr[16], myc[16];
  float myv[16];
#pragma unroll
  for (int k = 0; k < 16; ++k) {
    const int i = t + k * 256;
    myr[k] = -1;
    if (i < nloc) {
      myr[k] = rows[ebase + i];
      myc[k] = cols[ebase + i];
      myv[k] = vals[ebase + i];
      atomicAdd(&sm->hist[myr[k] >> SBSHIFT], 1);
    }
  }
  __syncthreads();

  // wave-0 exclusive scan of hist[196]: 4 values/lane, no barriers inside
  if (t < 64) {
    int v[4];
    int ssum = 0;
#pragma unroll
    for (int k = 0; k < 4; ++k) {
      const int g = t * 4 + k;
      v[k] = (g < SB) ? sm->hist[g] : 0;
      ssum += v[k];
    }
    int run = ssum;
#pragma unroll
    for (int off = 1; off < 64; off <<= 1) {
      const int u = __shfl_up(run, off);
      if (t >= off) run += u;
    }
    int excl = run - ssum;
#pragma unroll
    for (int k = 0; k < 4; ++k) {
      const int g = t * 4 + k;
      if (g < SB) {
        sm->lstart[g] = excl;
        sm->lpos[g] = excl;
      }
      excl += v[k];
    }
  }
  __syncthreads();

#pragma unroll
  for (int k = 0; k < 16; ++k) {
    if (myr[k] >= 0) {
      const int sb = myr[k] >> SBSHIFT;
      const int p = atomicAdd(&sm->lpos[sb], 1);
      sm->stage[p] =
          make_int2(myc[k] | ((myr[k] & (SBROWS - 1)) << 16) | (sb << 24),
                    __float_as_int(myv[k]));
    }
  }
  if (t < SB && sm->hist[t] > 0) {
    const int seg = sup * SB + t;
    const int bump = atomicAdd(&fillc[seg], sm->hist[t]);
    sm->gbase[t] = (CAPPED ? seg * CAP : 0) + bump;
  }
  __syncthreads();

  for (int i = t; i < nloc; i += 256) {
    const int2 ev = sm->stage[i];
    const int sb = ((unsigned)ev.x) >> 24;
    cv[sm->gbase[sb] + (i - sm->lstart[sb])] = ev;
  }
}

// ============================================================================
// Tier A init: blocks 0..15 pack W, block 16 zeroes fillc[392].
// ============================================================================
__global__ __launch_bounds__(256) void init_kernel(
    const float* __restrict__ W0, const float* __restrict__ W1,
    unsigned short* __restrict__ wpack, int* __restrict__ fillc) {
  const int t = threadIdx.x;
  if (blockIdx.x == 16) {
    if (t < NSEG) fillc[t] = 0;
    if (t + 256 < NSEG) fillc[t + 256] = 0;
    return;
  }
  wpack_one(blockIdx.x * 256 + t, W0, W1, wpack);
}

// ============================================================================
// Tier A launch 2 (round-11 pairing): bin (CAPPED, blocks 0..293) + ALL gemm
// tiles (blocks 294..1075). 256 threads; LDS union 35.1 KB -> 4 blocks/CU.
// ============================================================================
union BinGemmSmem {
  BinSmem bin;                   // ~35.1 KB
  unsigned short sbuf[64][136];  // 17.4 KB
};

template <bool CAPPED>
__global__ __launch_bounds__(256) void bingemm_kernel(
    const int* __restrict__ rows0, const int* __restrict__ cols0,
    const float* __restrict__ vals0, const int* __restrict__ rows1,
    const int* __restrict__ cols1, const float* __restrict__ vals1,
    int* __restrict__ fillc, int2* __restrict__ cv,
    const float* __restrict__ x, const unsigned short* __restrict__ wpack,
    unsigned short* __restrict__ preb) {
  __shared__ BinGemmSmem sm;
  const int bx = blockIdx.x;
  if (bx >= 2 * BIN_BLOCKS) {
    gemm_body64((bx - 2 * BIN_BLOCKS) * 64, x, wpack, preb, sm.sbuf);
    return;
  }
  bin_body<CAPPED>(bx, rows0, cols0, vals0, rows1, cols1, vals1, fillc, cv,
                   &sm.bin);
}

// ============================================================================
// Tier A sort: 392 blocks x 1024 thr (1.5 blocks/CU vs round-11's 0.77).
// ============================================================================
__global__ __launch_bounds__(1024) void sortA_kernel(
    const int* __restrict__ fillc, int2* __restrict__ cv,
    int* __restrict__ rs_s, int* __restrict__ rs_e) {
  __shared__ int cnt[SBROWS];
  __shared__ int base[SBROWS];
  __shared__ int off[SBROWS];
  const int sb = blockIdx.x;
  const int sup = blockIdx.y;
  const int seg = sup * SB + sb;
  sort_body(sup, sb, seg * CAP, fillc[seg], cv, rs_s, rs_e, cnt, base, off);
}

// ============================================================================
// Tier B: histogram + W prepack
// ============================================================================
__global__ __launch_bounds__(256) void histpack_kernel(
    const int* __restrict__ rows0, const int* __restrict__ rows1,
    int* __restrict__ cnt, const float* __restrict__ W0,
    const float* __restrict__ W1, unsigned short* __restrict__ wpack) {
  const int t = threadIdx.x;
  if (blockIdx.x >= HIST_BLOCKS) {
    wpack_one(((blockIdx.x - HIST_BLOCKS) + 8 * blockIdx.y) * 256 + t, W0, W1,
              wpack);
    return;
  }
  __shared__ int h[SB];
  if (t < SB) h[t] = 0;
  __syncthreads();
  const int sup = blockIdx.y;
  const int* rows = sup ? rows1 : rows0;
  int e = blockIdx.x * HISTBLK + t;
#pragma unroll
  for (int k = 0; k < HISTBLK / 256; ++k, e += 256)
    if (e < N_EDGES) atomicAdd(&h[rows[e] >> SBSHIFT], 1);
  __syncthreads();
  if (t < SB && h[t] > 0) atomicAdd(&cnt[sup * SB + t], h[t]);
}

// ============================================================================
// Tier B: exclusive scan of the 392 segment counts — single wave, 7/lane
// ============================================================================
__global__ __launch_bounds__(64) void scanseg_kernel(
    const int* __restrict__ cnt, int* __restrict__ fillc,
    int* __restrict__ sbstart) {
  const int t = threadIdx.x;
  int v[7];
  int ssum = 0;
#pragma unroll
  for (int k = 0; k < 7; ++k) {
    const int g = t * 7 + k;
    v[k] = (g < NSEG) ? cnt[g] : 0;
    ssum += v[k];
  }
  int run = ssum;
#pragma unroll
  for (int off = 1; off < 64; off <<= 1) {
    const int u = __shfl_up(run, off);
    if (t >= off) run += u;
  }
  int excl = run - ssum;
#pragma unroll
  for (int k = 0; k < 7; ++k) {
    const int g = t * 7 + k;
    if (g < NSEG) {
      fillc[g] = excl;
      sbstart[g] = excl;
    }
    excl += v[k];
  }
  if (t == 63) sbstart[NSEG] = 2 * N_EDGES;
}

// ============================================================================
// Tier B: standalone sort (exact bases)
// ============================================================================
__global__ __launch_bounds__(1024) void sortB_kernel(
    const int* __restrict__ sbstart, int2* __restrict__ cv,
    int* __restrict__ rs_s, int* __restrict__ rs_e) {
  __shared__ int cnt[SBROWS];
  __shared__ int base[SBROWS];
  __shared__ int off[SBROWS];
  const int sb = blockIdx.x;
  const int sup = blockIdx.y;
  const int seg = sup * SB + sb;
  const int s = sbstart[seg];
  const int n = sbstart[seg + 1] - s;
  sort_body(sup, sb, s, n, cv, rs_s, rs_e, cnt, base, off);
}

// ============================================================================
// Fused SpMM gather: persistent waves, both supports + bias + relu.
// ============================================================================
__global__ __launch_bounds__(256) void spmm_fused_kernel(
    const int* __restrict__ rs_s, const int* __restrict__ rs_e,
    const int2* __restrict__ cv, const unsigned short* __restrict__ preb,
    const float* __restrict__ bias, float* __restrict__ out) {
  const int lane = threadIdx.x & 63;
  const int g = lane >> 4;
  const int dbase = (lane & 15) << 3;
  const int wid = blockIdx.x * 4 + (threadIdx.x >> 6);

  const float4 b0 = *(const float4*)(bias + dbase);
  const float4 b1 = *(const float4*)(bias + dbase + 4);

  for (int row = wid; row < N_NODES; row += SPMM_WAVES) {
    float acc[8];
#pragma unroll
    for (int i = 0; i < 8; ++i) acc[i] = 0.f;

#pragma unroll
    for (int sup = 0; sup < 2; ++sup) {
      const int s = rs_s[sup * N_NODES + row];
      const int e = rs_e[sup * N_NODES + row];
      const unsigned short* pb = preb + (size_t)sup * N_NODES * D;
      int j = s + g;
      for (; j + 4 < e; j += 8) {
        const int2 e0 = cv[j];
        const int2 e1 = cv[j + 4];
        const uint4 q0 = *(const uint4*)(pb + (size_t)(e0.x & 0xFFFF) * D + dbase);
        const uint4 q1 = *(const uint4*)(pb + (size_t)(e1.x & 0xFFFF) * D + dbase);
        const float v0 = __int_as_float(e0.y);
        const float v1 = __int_as_float(e1.y);
        acc[0] = fmaf(v0, __uint_as_float(q0.x << 16), acc[0]);
        acc[1] = fmaf(v0, __uint_as_float(q0.x & 0xFFFF0000u), acc[1]);
        acc[2] = fmaf(v0, __uint_as_float(q0.y << 16), acc[2]);
        acc[3] = fmaf(v0, __uint_as_float(q0.y & 0xFFFF0000u), acc[3]);
        acc[4] = fmaf(v0, __uint_as_float(q0.z << 16), acc[4]);
        acc[5] = fmaf(v0, __uint_as_float(q0.z & 0xFFFF0000u), acc[5]);
        acc[6] = fmaf(v0, __uint_as_float(q0.w << 16), acc[6]);
        acc[7] = fmaf(v0, __uint_as_float(q0.w & 0xFFFF0000u), acc[7]);
        acc[0] = fmaf(v1, __uint_as_float(q1.x << 16), acc[0]);
        acc[1] = fmaf(v1, __uint_as_float(q1.x & 0xFFFF0000u), acc[1]);
        acc[2] = fmaf(v1, __uint_as_float(q1.y << 16), acc[2]);
        acc[3] = fmaf(v1, __uint_as_float(q1.y & 0xFFFF0000u), acc[3]);
        acc[4] = fmaf(v1, __uint_as_float(q1.z << 16), acc[4]);
        acc[5] = fmaf(v1, __uint_as_float(q1.z & 0xFFFF0000u), acc[5]);
        acc[6] = fmaf(v1, __uint_as_float(q1.w << 16), acc[6]);
        acc[7] = fmaf(v1, __uint_as_float(q1.w & 0xFFFF0000u), acc[7]);
      }
      if (j < e) {
        const int2 e0 = cv[j];
        const uint4 q0 = *(const uint4*)(pb + (size_t)(e0.x & 0xFFFF) * D + dbase);
        const float v0 = __int_as_float(e0.y);
        acc[0] = fmaf(v0, __uint_as_float(q0.x << 16), acc[0]);
        acc[1] = fmaf(v0, __uint_as_float(q0.x & 0xFFFF0000u), acc[1]);
        acc[2] = fmaf(v0, __uint_as_float(q0.y << 16), acc[2]);
        acc[3] = fmaf(v0, __uint_as_float(q0.y & 0xFFFF0000u), acc[3]);
        acc[4] = fmaf(v0, __uint_as_float(q0.z << 16), acc[4]);
        acc[5] = fmaf(v0, __uint_as_float(q0.z & 0xFFFF0000u), acc[5]);
        acc[6] = fmaf(v0, __uint_as_float(q0.w << 16), acc[6]);
        acc[7] = fmaf(v0, __uint_as_float(q0.w & 0xFFFF0000u), acc[7]);
      }
    }

#pragma unroll
    for (int i = 0; i < 8; ++i) {
      acc[i] += __shfl_xor(acc[i], 16);
      acc[i] += __shfl_xor(acc[i], 32);
    }

    if (g == 0) {
      float4 r0, r1;
      r0.x = fmaxf(acc[0] + b0.x, 0.f);
      r0.y = fmaxf(acc[1] + b0.y, 0.f);
      r0.z = fmaxf(acc[2] + b0.z, 0.f);
      r0.w = fmaxf(acc[3] + b0.w, 0.f);
      r1.x = fmaxf(acc[4] + b1.x, 0.f);
      r1.y = fmaxf(acc[5] + b1.y, 0.f);
      r1.z = fmaxf(acc[6] + b1.z, 0.f);
      r1.w = fmaxf(acc[7] + b1.w, 0.f);
      float* op = out + (size_t)row * D + dbase;
      *(float4*)op = r0;
      *(float4*)(op + 4) = r1;
    }
  }
}

// ============================================================================
// Fallback: fp32 gemm + atomic scatter (used only if workspace too small)
// ============================================================================
__global__ __launch_bounds__(256) void gemm_f32_kernel(
    const float* __restrict__ x, const float* __restrict__ W,
    float* __restrict__ pre) {
  const int tid = threadIdx.x;
  const int nloc = (tid >> 5) << 3;
  const int d4 = (tid & 31) << 2;
  const int nbase = blockIdx.x * 64;
  __shared__ float xs[64][D];
  {
    float4* xs4 = (float4*)(&xs[0][0]);
    const float4* xg4 = (const float4*)x;
#pragma unroll
    for (int i = 0; i < 8; ++i) {
      const int idx = tid + i * 256;
      const int row = nbase + (idx >> 5);
      xs4[idx] = (row < N_NODES) ? xg4[(size_t)row * 32 + (idx & 31)]
                                 : make_float4(0.f, 0.f, 0.f, 0.f);
    }
  }
  __syncthreads();
  float4 acc[8];
#pragma unroll
  for (int i = 0; i < 8; ++i) acc[i] = make_float4(0.f, 0.f, 0.f, 0.f);
  for (int k = 0; k < D; ++k) {
    const float4 w = *(const float4*)(W + k * D + d4);
#pragma unroll
    for (int i = 0; i < 8; ++i) {
      const float xv = xs[nloc + i][k];
      acc[i].x = fmaf(xv, w.x, acc[i].x);
      acc[i].y = fmaf(xv, w.y, acc[i].y);
      acc[i].z = fmaf(xv, w.z, acc[i].z);
      acc[i].w = fmaf(xv, w.w, acc[i].w);
    }
  }
#pragma unroll
  for (int i = 0; i < 8; ++i) {
    const int n = nbase + nloc + i;
    if (n < N_NODES) *(float4*)(pre + (size_t)n * D + d4) = acc[i];
  }
}

__global__ __launch_bounds__(256) void spmm_scatter_kernel(
    const int* __restrict__ rows, const int* __restrict__ cols,
    const float* __restrict__ vals, const float* __restrict__ pre,
    float* __restrict__ out) {
  const long long idx = (long long)blockIdx.x * blockDim.x + threadIdx.x;
  const int e = (int)(idx >> 6);
  if (e >= N_EDGES) return;
  const int dd = ((int)idx & 63) << 1;
  const int r = rows[e];
  const int c = cols[e];
  const float v = vals[e];
  const float2 p = *(const float2*)(pre + (size_t)c * D + dd);
  float* outp = out + (size_t)r * D + dd;
  atomicAdd(outp + 0, v * p.x);
  atomicAdd(outp + 1, v * p.y);
}

__global__ __launch_bounds__(256) void bias_relu_kernel(
    float* __restrict__ out, const float* __restrict__ b) {
  const int idx = blockIdx.x * blockDim.x + threadIdx.x;
  float4 v = ((float4*)out)[idx];
  const float4 bb = ((const float4*)b)[idx & 31];
  v.x = fmaxf(v.x + bb.x, 0.f);
  v.y = fmaxf(v.y + bb.y, 0.f);
  v.z = fmaxf(v.z + bb.z, 0.f);
  v.w = fmaxf(v.w + bb.w, 0.f);
  ((float4*)out)[idx] = v;
}

extern "C" void kernel_launch(void* const* d_in, const int* in_sizes, int n_in,
                              void* d_out, int out_size, void* d_ws,
                              size_t ws_size, hipStream_t stream) {
  const float* x = (const float*)d_in[0];
  const float* W0 = (const float*)d_in[1];
  const float* W1 = (const float*)d_in[2];
  const float* b = (const float*)d_in[3];
  const int* rows0 = (const int*)d_in[4];
  const int* cols0 = (const int*)d_in[5];
  const float* vals0 = (const float*)d_in[6];
  const int* rows1 = (const int*)d_in[7];
  const int* cols1 = (const int*)d_in[8];
  const float* vals1 = (const float*)d_in[9];
  float* out = (float*)d_out;

  auto align_up = [](size_t v) { return (v + 255) & ~(size_t)255; };
  const size_t PREB = align_up((size_t)2 * N_NODES * D * 2);  // 25.6 MB bf16
  const size_t FILLC = align_up((size_t)NSEG * 4);
  const size_t RS1 = align_up((size_t)2 * N_NODES * 4);  // 400 KB each
  const size_t WPACK = align_up((size_t)2 * D * D * 2);  // 64 KB

  // Tier A: fixed-capacity segments (no hist/scan/memset)
  const size_t CVC = align_up((size_t)NSEG * CAP * 8);  // 12.85 MB
  const size_t NEED_A = PREB + CVC + FILLC + 2 * RS1 + WPACK;  // ~39.4 MB
  // Tier B: exact bases
  const size_t CV = align_up((size_t)2 * N_EDGES * 8);  // 9.6 MB
  const size_t CNT = align_up((size_t)NSEG * 4);
  const size_t SBSTART = align_up((size_t)(NSEG + 1) * 4);
  const size_t NEED_B = PREB + CV + CNT + FILLC + SBSTART + 2 * RS1 + WPACK;

  char* wsc = (char*)d_ws;

  if (ws_size >= NEED_A) {
    unsigned short* preb = (unsigned short*)wsc;
    int2* cv = (int2*)(wsc + PREB);
    int* fillc = (int*)(wsc + PREB + CVC);
    int* rs_s = (int*)(wsc + PREB + CVC + FILLC);
    int* rs_e = (int*)(wsc + PREB + CVC + FILLC + RS1);
    unsigned short* wpack =
        (unsigned short*)(wsc + PREB + CVC + FILLC + 2 * RS1);

    init_kernel<<<17, 256, 0, stream>>>(W0, W1, wpack, fillc);
    bingemm_kernel<true><<<2 * BIN_BLOCKS + GEMM_BLOCKS, 256, 0, stream>>>(
        rows0, cols0, vals0, rows1, cols1, vals1, fillc, cv, x, wpack, preb);
    sortA_kernel<<<dim3(SB, 2), 1024, 0, stream>>>(fillc, cv, rs_s, rs_e);
    spmm_fused_kernel<<<SPMM_BLOCKS, 256, 0, stream>>>(rs_s, rs_e, cv, preb, b,
                                                       out);
  } else if (ws_size >= NEED_B) {
    unsigned short* preb = (unsigned short*)wsc;
    int2* cv = (int2*)(wsc + PREB);
    int* cnt = (int*)(wsc + PREB + CV);
    int* fillc = (int*)(wsc + PREB + CV + CNT);
    int* sbstart = (int*)(wsc + PREB + CV + CNT + FILLC);
    int* rs_s = (int*)(wsc + PREB + CV + CNT + FILLC + SBSTART);
    int* rs_e = (int*)(wsc + PREB + CV + CNT + FILLC + SBSTART + RS1);
    unsigned short* wpack =
        (unsigned short*)(wsc + PREB + CV + CNT + FILLC + SBSTART + 2 * RS1);

    hipMemsetAsync(cnt, 0, (size_t)NSEG * 4, stream);
    histpack_kernel<<<dim3(HIST_BLOCKS + 8, 2), 256, 0, stream>>>(
        rows0, rows1, cnt, W0, W1, wpack);
    scanseg_kernel<<<1, 64, 0, stream>>>(cnt, fillc, sbstart);
    bingemm_kernel<false><<<2 * BIN_BLOCKS + GEMM_BLOCKS, 256, 0, stream>>>(
        rows0, cols0, vals0, rows1, cols1, vals1, fillc, cv, x, wpack, preb);
    sortB_kernel<<<dim3(SB, 2), 1024, 0, stream>>>(sbstart, cv, rs_s, rs_e);
    spmm_fused_kernel<<<SPMM_BLOCKS, 256, 0, stream>>>(rs_s, rs_e, cv, preb, b,
                                                       out);
  } else {
    float* pre = (float*)wsc;
    hipMemsetAsync(d_out, 0, (size_t)N_NODES * D * 4, stream);
    const int scat_blocks = (N_EDGES * 64 + 255) / 256;
    gemm_f32_kernel<<<GEMM_BLOCKS, 256, 0, stream>>>(x, W0, pre);
    spmm_scatter_kernel<<<scat_blocks, 256, 0, stream>>>(rows0, cols0, vals0,
                                                         pre, out);
    gemm_f32_kernel<<<GEMM_BLOCKS, 256, 0, stream>>>(x, W1, pre);
    spmm_scatter_kernel<<<scat_blocks, 256, 0, stream>>>(rows1, cols1, vals1,
                                                         pre, out);
    bias_relu_kernel<<<(N_NODES * D / 4) / 256, 256, 0, stream>>>(out, b);
  }
}